// Round 3
// baseline (1105.509 us; speedup 1.0000x reference)
//
#include <hip/hip_runtime.h>
#include <math.h>

#define NPTS   65536
#define DIM    128
#define KCODES 4096

constexpr float DECAY_F         = 0.99f;
constexpr float ONE_MINUS_DECAY = 0.01f;
constexpr float EPS_F           = 1e-5f;

// d_out layout (floats): quantize_st[N*D] | embed_ind[N] | loss[1] | new_embed[K*D] | new_cluster_size[K]
constexpr int OFF_IDX  = NPTS * DIM;
constexpr int OFF_LOSS = OFF_IDX + NPTS;
constexpr int OFF_EMB  = OFF_LOSS + 1;
constexpr int OFF_NCS  = OFF_EMB + KCODES * DIM;

typedef _Float16 half8 __attribute__((ext_vector_type(8)));
typedef _Float16 half4 __attribute__((ext_vector_type(4)));
typedef float    f32x4 __attribute__((ext_vector_type(4)));

// ---------------- esq: exact fp32 |e|^2, one wave per code ----------------
__global__ __launch_bounds__(256) void vq_esq_kernel(const float* __restrict__ embed,
                                                     float* __restrict__ esq) {
    int tid  = threadIdx.x;
    int k    = blockIdx.x * 4 + (tid >> 6);
    int lane = tid & 63;
    float v0 = embed[k * DIM + lane];
    float v1 = embed[k * DIM + 64 + lane];
    float s  = v0 * v0 + v1 * v1;
#pragma unroll
    for (int off = 32; off >= 1; off >>= 1) s += __shfl_down(s, off);
    if (lane == 0) esq[k] = s;
}

// ---------------- E image: per-32-code tile, pre-swizzled LDS image ----------------
// tile image (16 KB): hi[32 rows][256B swizzled] @0, lo same @8192.
// un-swizzled byte c8*16 of row r holds k-elems [c8*8, c8*8+8); swizzle: ^((r&7)<<4).
__global__ __launch_bounds__(256) void vq_eimg_kernel(const float* __restrict__ embed,
                                                      unsigned char* __restrict__ Eimg) {
    int tile = blockIdx.x, t = threadIdx.x;
    unsigned char* img = Eimg + ((size_t)tile << 14);
#pragma unroll
    for (int it = 0; it < 2; ++it) {
        int idx = t + it * 256;            // 0..511
        int r = idx >> 4, c8 = idx & 15;
        const float4* src = (const float4*)(embed + (size_t)(tile * 32 + r) * DIM + c8 * 8);
        float4 v0 = src[0], v1 = src[1];
        float e[8] = {v0.x, v0.y, v0.z, v0.w, v1.x, v1.y, v1.z, v1.w};
        half8 h8, l8;
#pragma unroll
        for (int j = 0; j < 8; ++j) {
            _Float16 h = (_Float16)e[j];
            h8[j] = h;
            l8[j] = (_Float16)(e[j] - (float)h);
        }
        int bo = r * 256 + ((c8 * 16) ^ ((r & 7) << 4));
        *(half8*)(img + bo)        = h8;
        *(half8*)(img + 8192 + bo) = l8;
    }
}

// ---------------- main: K-split MFMA distance argmin -> per-half partials ----------------
// grid 1024: mblk = bid>>1 (128 rows), half = bid&1 (2048 codes).
// 4 waves; wave owns 32 rows (2 frags); E: 32-code tiles, 16KB dbuf, global_load_lds staging.
__global__ __launch_bounds__(256, 4)
void vq_main_kernel(const float* __restrict__ x, const float* __restrict__ esq,
                    const unsigned char* __restrict__ Eimg,
                    float* __restrict__ pmin, int* __restrict__ pidx) {
    __shared__ __align__(16) unsigned char lds[32768];

    const int tid  = threadIdx.x;
    const int l    = tid & 63;
    const int w    = tid >> 6;
    const int mblk = blockIdx.x >> 1;
    const int half = blockIdx.x & 1;
    const int row0 = mblk * 128;

    // ---- X prologue: two 64-row phases through LDS; A = -2x f16 hi/lo -> registers ----
    half8 ahi[2][4], alo[2][4];
#pragma unroll
    for (int ph = 0; ph < 2; ++ph) {
        if (ph) __syncthreads();
        const float4* xg = (const float4*)(x + (size_t)(row0 + ph * 64) * DIM);
#pragma unroll
        for (int it = 0; it < 8; ++it) {
            int i4 = tid + it * 256;           // 0..2047 : 64 rows x 32 f4
            int r = i4 >> 5, c4 = i4 & 31;
            float4 v = xg[i4];
            float m0 = -2.f * v.x, m1 = -2.f * v.y, m2 = -2.f * v.z, m3 = -2.f * v.w;
            half4 h, lo;
            h[0] = (_Float16)m0; h[1] = (_Float16)m1; h[2] = (_Float16)m2; h[3] = (_Float16)m3;
            lo[0] = (_Float16)(m0 - (float)h[0]); lo[1] = (_Float16)(m1 - (float)h[1]);
            lo[2] = (_Float16)(m2 - (float)h[2]); lo[3] = (_Float16)(m3 - (float)h[3]);
            int bo = r * 256 + ((c4 * 8) ^ ((r & 7) << 4));
            *(half4*)(lds + bo)         = h;
            *(half4*)(lds + 16384 + bo) = lo;
        }
        __syncthreads();
        if ((w >> 1) == ph) {
#pragma unroll
            for (int rf = 0; rf < 2; ++rf)
#pragma unroll
                for (int ks = 0; ks < 4; ++ks) {
                    int rloc = (w & 1) * 32 + rf * 16 + (l & 15);
                    int bo = rloc * 256 + ((ks * 64 + (l >> 4) * 16) ^ ((rloc & 7) << 4));
                    ahi[rf][ks] = *(const half8*)(lds + bo);
                    alo[rf][ks] = *(const half8*)(lds + 16384 + bo);
                }
        }
    }
    __syncthreads();   // frag loads done; lds becomes E double-buffer (16KB each)

    // async staging: pre-swizzled image, linear LDS dest (wave-uniform base + lane*16)
#define STAGE(P, CT)                                                                     \
    {                                                                                    \
        const unsigned char* gsrc = Eimg + ((size_t)(half * 64 + (CT)) << 14);           \
        _Pragma("unroll")                                                                \
        for (int t = 0; t < 4; ++t) {                                                    \
            __builtin_amdgcn_global_load_lds(                                            \
                (const __attribute__((address_space(1))) unsigned int*)(gsrc + t * 4096 + w * 1024 + l * 16), \
                (__attribute__((address_space(3))) unsigned int*)(lds + (P) * 16384 + t * 4096 + w * 1024),   \
                16, 0, 0);                                                               \
        }                                                                                \
    }

    float minv[2][4];
    int   mini[2][4];
#pragma unroll
    for (int rf = 0; rf < 2; ++rf)
#pragma unroll
        for (int r = 0; r < 4; ++r) { minv[rf][r] = 3.4e38f; mini[rf][r] = 0; }

    STAGE(0, 0);
    __syncthreads();

    for (int ct = 0; ct < 64; ++ct) {
        int p = ct & 1;
        if (ct < 63) STAGE(p ^ 1, ct + 1);
        const unsigned char* bb = lds + p * 16384;

        float ecf[2];
#pragma unroll
        for (int cf = 0; cf < 2; ++cf) ecf[cf] = esq[half * 2048 + ct * 32 + cf * 16 + (l & 15)];

        f32x4 acc[2][2];
#pragma unroll
        for (int rf = 0; rf < 2; ++rf)
#pragma unroll
            for (int cf = 0; cf < 2; ++cf) acc[rf][cf] = (f32x4){0.f, 0.f, 0.f, 0.f};

#pragma unroll
        for (int ks = 0; ks < 4; ++ks) {
#pragma unroll
            for (int cf = 0; cf < 2; ++cf) {
                int rowb = cf * 16 + (l & 15);
                int bo = rowb * 256 + ((ks * 64 + (l >> 4) * 16) ^ ((rowb & 7) << 4));
                half8 bh = *(const half8*)(bb + bo);
                half8 bl = *(const half8*)(bb + 8192 + bo);
                acc[0][cf] = __builtin_amdgcn_mfma_f32_16x16x32_f16(ahi[0][ks], bh, acc[0][cf], 0, 0, 0);
                acc[1][cf] = __builtin_amdgcn_mfma_f32_16x16x32_f16(ahi[1][ks], bh, acc[1][cf], 0, 0, 0);
                acc[0][cf] = __builtin_amdgcn_mfma_f32_16x16x32_f16(alo[0][ks], bh, acc[0][cf], 0, 0, 0);
                acc[1][cf] = __builtin_amdgcn_mfma_f32_16x16x32_f16(alo[1][ks], bh, acc[1][cf], 0, 0, 0);
                acc[0][cf] = __builtin_amdgcn_mfma_f32_16x16x32_f16(ahi[0][ks], bl, acc[0][cf], 0, 0, 0);
                acc[1][cf] = __builtin_amdgcn_mfma_f32_16x16x32_f16(ahi[1][ks], bl, acc[1][cf], 0, 0, 0);
            }
        }

#pragma unroll
        for (int rf = 0; rf < 2; ++rf)
#pragma unroll
            for (int cf = 0; cf < 2; ++cf) {
                int kidx = half * 2048 + ct * 32 + cf * 16 + (l & 15);
#pragma unroll
                for (int r = 0; r < 4; ++r) {
                    float v = ecf[cf] + acc[rf][cf][r];
                    if (v < minv[rf][r]) { minv[rf][r] = v; mini[rf][r] = kidx; }
                }
            }

        __syncthreads();   // drains staging vmcnt + protects buffer reuse
    }

    // argmin reduce across the 16 col-lanes (low 4 lane bits)
#pragma unroll
    for (int off = 1; off < 16; off <<= 1) {
#pragma unroll
        for (int rf = 0; rf < 2; ++rf)
#pragma unroll
            for (int r = 0; r < 4; ++r) {
                float v2 = __shfl_xor(minv[rf][r], off);
                int   i2 = __shfl_xor(mini[rf][r], off);
                if (v2 < minv[rf][r] || (v2 == minv[rf][r] && i2 < mini[rf][r])) {
                    minv[rf][r] = v2; mini[rf][r] = i2;
                }
            }
    }
    if ((l & 15) == 0) {
#pragma unroll
        for (int rf = 0; rf < 2; ++rf)
#pragma unroll
            for (int r = 0; r < 4; ++r) {
                int row = row0 + w * 32 + rf * 16 + (l >> 4) * 4 + r;   // C/D: row=(l>>4)*4+reg
                pmin[(size_t)half * NPTS + row] = minv[rf][r];
                pidx[(size_t)half * NPTS + row] = mini[rf][r];
            }
    }
}

// ---------------- combine: select half, gather quantize, loss, scatter ----------------
// 1024 blocks x 256 thr; 4 threads per row (32 dims each).
__global__ __launch_bounds__(256) void vq_combine_kernel(const float* __restrict__ x,
                                                         const float* __restrict__ embed,
                                                         const float* __restrict__ pmin,
                                                         const int* __restrict__ pidx,
                                                         float* __restrict__ out) {
    __shared__ float red[256];
    int tid = threadIdx.x;
    int r   = blockIdx.x * 64 + (tid >> 2);
    int dq  = (tid & 3) * 8;               // float4 index base within row

    float m0 = pmin[r], m1 = pmin[NPTS + r];
    int   k  = (m0 <= m1) ? pidx[r] : pidx[NPTS + r];
    if ((tid & 3) == 0) {
        out[OFF_IDX + r] = (float)k;
        atomicAdd(&out[OFF_NCS + k], 1.0f);
    }

    const float4* eg = (const float4*)embed + (size_t)k * 32 + dq;
    const float4* xg = (const float4*)x + (size_t)r * 32 + dq;
    float4*       qg = (float4*)out + (size_t)r * 32 + dq;
    float*        ea = out + OFF_EMB + (size_t)k * DIM + dq * 4;

    float lsum = 0.f;
#pragma unroll
    for (int j = 0; j < 8; ++j) {
        float4 q = eg[j], xv = xg[j];
        qg[j] = q;
        float d0 = q.x - xv.x, d1 = q.y - xv.y, d2 = q.z - xv.z, d3 = q.w - xv.w;
        lsum += d0 * d0 + d1 * d1 + d2 * d2 + d3 * d3;
        atomicAdd(ea + j * 4 + 0, xv.x);
        atomicAdd(ea + j * 4 + 1, xv.y);
        atomicAdd(ea + j * 4 + 2, xv.z);
        atomicAdd(ea + j * 4 + 3, xv.w);
    }
    red[tid] = lsum;
    __syncthreads();
    for (int s = 128; s >= 1; s >>= 1) {
        if (tid < s) red[tid] += red[tid + s];
        __syncthreads();
    }
    if (tid == 0) atomicAdd(out + OFF_LOSS, red[0]);
}

// ---------------- finalize cluster sizes, n_total, inv_smoothed, loss scale ----------------
__global__ __launch_bounds__(256) void vq_finalize_kernel(const float* __restrict__ cs,
                                                          float* __restrict__ out,
                                                          float* __restrict__ inv_sm) {
    __shared__ float red[256];
    float* ncs    = out + OFF_NCS;
    float* loss_p = out + OFF_LOSS;
    int tid = threadIdx.x;
    float vloc[16];
    float part = 0.f;
#pragma unroll
    for (int it = 0; it < 16; ++it) {
        int k = tid + it * 256;
        float v = fmaf(cs[k], DECAY_F, ncs[k] * ONE_MINUS_DECAY);
        vloc[it] = v;
        ncs[k] = v;
        part += v;
    }
    red[tid] = part;
    __syncthreads();
    for (int s = 128; s >= 1; s >>= 1) {
        if (tid < s) red[tid] += red[tid + s];
        __syncthreads();
    }
    float ntot = red[0];
    float num  = ntot + (float)KCODES * EPS_F;
#pragma unroll
    for (int it = 0; it < 16; ++it) {
        int k = tid + it * 256;
        inv_sm[k] = num / ((vloc[it] + EPS_F) * ntot);
    }
    if (tid == 0) loss_p[0] = loss_p[0] * (1.0f / ((float)NPTS * (float)DIM));
}

// ---------------- new_embed = (embed_avg*0.99 + embed_sum*0.01) / smoothed ----------------
__global__ __launch_bounds__(256) void vq_embed_kernel(const float* __restrict__ eavg,
                                                       const float* __restrict__ inv_sm,
                                                       float* __restrict__ out) {
    float* emb = out + OFF_EMB;
    int i = blockIdx.x * 256 + threadIdx.x;
    int k = i >> 7;
    float v = fmaf(eavg[i], DECAY_F, emb[i] * ONE_MINUS_DECAY);
    emb[i] = v * inv_sm[k];
}

extern "C" void kernel_launch(void* const* d_in, const int* in_sizes, int n_in,
                              void* d_out, int out_size, void* d_ws, size_t ws_size,
                              hipStream_t stream) {
    const float* x     = (const float*)d_in[0];
    const float* embed = (const float*)d_in[1];
    const float* cs    = (const float*)d_in[2];
    const float* eavg  = (const float*)d_in[3];
    float* out = (float*)d_out;

    // ws: esq[4096] | inv_sm[4096] | pmin[2*N] | pidx[2*N] int | Eimg 2MB  (~3.1 MB)
    float*         esq    = (float*)d_ws;
    float*         inv_sm = esq + KCODES;
    float*         pmin   = inv_sm + KCODES;
    int*           pidx   = (int*)(pmin + 2 * NPTS);
    unsigned char* Eimg   = (unsigned char*)(pidx + 2 * NPTS);

    hipMemsetAsync(out + OFF_LOSS, 0, (size_t)(1 + KCODES * DIM + KCODES) * sizeof(float), stream);

    vq_esq_kernel<<<KCODES / 4, 256, 0, stream>>>(embed, esq);
    vq_eimg_kernel<<<KCODES / 32, 256, 0, stream>>>(embed, Eimg);
    vq_main_kernel<<<NPTS / 128 * 2, 256, 0, stream>>>(x, esq, Eimg, pmin, pidx);
    vq_combine_kernel<<<NPTS / 64, 256, 0, stream>>>(x, embed, pmin, pidx, out);
    vq_finalize_kernel<<<1, 256, 0, stream>>>(cs, out, inv_sm);
    vq_embed_kernel<<<(KCODES * DIM) / 256, 256, 0, stream>>>(eavg, inv_sm, out);
}

// Round 4
// 384.520 us; speedup vs baseline: 2.8750x; 2.8750x over previous
//
#include <hip/hip_runtime.h>
#include <math.h>

#define NPTS   65536
#define DIM    128
#define KCODES 4096

constexpr float DECAY_F         = 0.99f;
constexpr float ONE_MINUS_DECAY = 0.01f;
constexpr float EPS_F           = 1e-5f;

// d_out layout (floats): quantize_st[N*D] | embed_ind[N] | loss[1] | new_embed[K*D] | new_cluster_size[K]
constexpr int OFF_IDX  = NPTS * DIM;
constexpr int OFF_LOSS = OFF_IDX + NPTS;
constexpr int OFF_EMB  = OFF_LOSS + 1;
constexpr int OFF_NCS  = OFF_EMB + KCODES * DIM;

typedef _Float16 half8 __attribute__((ext_vector_type(8)));
typedef _Float16 half4 __attribute__((ext_vector_type(4)));
typedef float    f32x4 __attribute__((ext_vector_type(4)));

// ---------------- esq: exact fp32 |e|^2, one wave per code ----------------
__global__ __launch_bounds__(256) void vq_esq_kernel(const float* __restrict__ embed,
                                                     float* __restrict__ esq) {
    int tid  = threadIdx.x;
    int k    = blockIdx.x * 4 + (tid >> 6);
    int lane = tid & 63;
    float v0 = embed[k * DIM + lane];
    float v1 = embed[k * DIM + 64 + lane];
    float s  = v0 * v0 + v1 * v1;
#pragma unroll
    for (int off = 32; off >= 1; off >>= 1) s += __shfl_down(s, off);
    if (lane == 0) esq[k] = s;
}

// ---------------- E image: per-32-code tile, pre-swizzled LDS image ----------------
__global__ __launch_bounds__(256) void vq_eimg_kernel(const float* __restrict__ embed,
                                                      unsigned char* __restrict__ Eimg) {
    int tile = blockIdx.x, t = threadIdx.x;
    unsigned char* img = Eimg + ((size_t)tile << 14);
#pragma unroll
    for (int it = 0; it < 2; ++it) {
        int idx = t + it * 256;            // 0..511
        int r = idx >> 4, c8 = idx & 15;
        const float4* src = (const float4*)(embed + (size_t)(tile * 32 + r) * DIM + c8 * 8);
        float4 v0 = src[0], v1 = src[1];
        float e[8] = {v0.x, v0.y, v0.z, v0.w, v1.x, v1.y, v1.z, v1.w};
        half8 h8, l8;
#pragma unroll
        for (int j = 0; j < 8; ++j) {
            _Float16 h = (_Float16)e[j];
            h8[j] = h;
            l8[j] = (_Float16)(e[j] - (float)h);
        }
        int bo = r * 256 + ((c8 * 16) ^ ((r & 7) << 4));
        *(half8*)(img + bo)        = h8;
        *(half8*)(img + 8192 + bo) = l8;
    }
}

// ---------------- main: K-split MFMA distance argmin -> per-half partials ----------------
__global__ __launch_bounds__(256, 4)
void vq_main_kernel(const float* __restrict__ x, const float* __restrict__ esq,
                    const unsigned char* __restrict__ Eimg,
                    float* __restrict__ pmin, int* __restrict__ pidx) {
    __shared__ __align__(16) unsigned char lds[32768];

    const int tid  = threadIdx.x;
    const int l    = tid & 63;
    const int w    = tid >> 6;
    const int mblk = blockIdx.x >> 1;
    const int half = blockIdx.x & 1;
    const int row0 = mblk * 128;

    // ---- X prologue: two 64-row phases through LDS; A = -2x f16 hi/lo -> registers ----
    half8 ahi[2][4], alo[2][4];
#pragma unroll
    for (int ph = 0; ph < 2; ++ph) {
        if (ph) __syncthreads();
        const float4* xg = (const float4*)(x + (size_t)(row0 + ph * 64) * DIM);
#pragma unroll
        for (int it = 0; it < 8; ++it) {
            int i4 = tid + it * 256;           // 0..2047 : 64 rows x 32 f4
            int r = i4 >> 5, c4 = i4 & 31;
            float4 v = xg[i4];
            float m0 = -2.f * v.x, m1 = -2.f * v.y, m2 = -2.f * v.z, m3 = -2.f * v.w;
            half4 h, lo;
            h[0] = (_Float16)m0; h[1] = (_Float16)m1; h[2] = (_Float16)m2; h[3] = (_Float16)m3;
            lo[0] = (_Float16)(m0 - (float)h[0]); lo[1] = (_Float16)(m1 - (float)h[1]);
            lo[2] = (_Float16)(m2 - (float)h[2]); lo[3] = (_Float16)(m3 - (float)h[3]);
            int bo = r * 256 + ((c4 * 8) ^ ((r & 7) << 4));
            *(half4*)(lds + bo)         = h;
            *(half4*)(lds + 16384 + bo) = lo;
        }
        __syncthreads();
        if ((w >> 1) == ph) {
#pragma unroll
            for (int rf = 0; rf < 2; ++rf)
#pragma unroll
                for (int ks = 0; ks < 4; ++ks) {
                    int rloc = (w & 1) * 32 + rf * 16 + (l & 15);
                    int bo = rloc * 256 + ((ks * 64 + (l >> 4) * 16) ^ ((rloc & 7) << 4));
                    ahi[rf][ks] = *(const half8*)(lds + bo);
                    alo[rf][ks] = *(const half8*)(lds + 16384 + bo);
                }
        }
    }
    __syncthreads();   // frag loads done; lds becomes E double-buffer (16KB each)

#define STAGE(P, CT)                                                                     \
    {                                                                                    \
        const unsigned char* gsrc = Eimg + ((size_t)(half * 64 + (CT)) << 14);           \
        _Pragma("unroll")                                                                \
        for (int t = 0; t < 4; ++t) {                                                    \
            __builtin_amdgcn_global_load_lds(                                            \
                (const __attribute__((address_space(1))) unsigned int*)(gsrc + t * 4096 + w * 1024 + l * 16), \
                (__attribute__((address_space(3))) unsigned int*)(lds + (P) * 16384 + t * 4096 + w * 1024),   \
                16, 0, 0);                                                               \
        }                                                                                \
    }

    float minv[2][4];
    int   mini[2][4];
#pragma unroll
    for (int rf = 0; rf < 2; ++rf)
#pragma unroll
        for (int r = 0; r < 4; ++r) { minv[rf][r] = 3.4e38f; mini[rf][r] = 0; }

    STAGE(0, 0);
    __syncthreads();

    for (int ct = 0; ct < 64; ++ct) {
        int p = ct & 1;
        if (ct < 63) STAGE(p ^ 1, ct + 1);
        const unsigned char* bb = lds + p * 16384;

        float ecf[2];
#pragma unroll
        for (int cf = 0; cf < 2; ++cf) ecf[cf] = esq[half * 2048 + ct * 32 + cf * 16 + (l & 15)];

        f32x4 acc[2][2];
#pragma unroll
        for (int rf = 0; rf < 2; ++rf)
#pragma unroll
            for (int cf = 0; cf < 2; ++cf) acc[rf][cf] = (f32x4){0.f, 0.f, 0.f, 0.f};

#pragma unroll
        for (int ks = 0; ks < 4; ++ks) {
#pragma unroll
            for (int cf = 0; cf < 2; ++cf) {
                int rowb = cf * 16 + (l & 15);
                int bo = rowb * 256 + ((ks * 64 + (l >> 4) * 16) ^ ((rowb & 7) << 4));
                half8 bh = *(const half8*)(bb + bo);
                half8 bl = *(const half8*)(bb + 8192 + bo);
                acc[0][cf] = __builtin_amdgcn_mfma_f32_16x16x32_f16(ahi[0][ks], bh, acc[0][cf], 0, 0, 0);
                acc[1][cf] = __builtin_amdgcn_mfma_f32_16x16x32_f16(ahi[1][ks], bh, acc[1][cf], 0, 0, 0);
                acc[0][cf] = __builtin_amdgcn_mfma_f32_16x16x32_f16(alo[0][ks], bh, acc[0][cf], 0, 0, 0);
                acc[1][cf] = __builtin_amdgcn_mfma_f32_16x16x32_f16(alo[1][ks], bh, acc[1][cf], 0, 0, 0);
                acc[0][cf] = __builtin_amdgcn_mfma_f32_16x16x32_f16(ahi[0][ks], bl, acc[0][cf], 0, 0, 0);
                acc[1][cf] = __builtin_amdgcn_mfma_f32_16x16x32_f16(ahi[1][ks], bl, acc[1][cf], 0, 0, 0);
            }
        }

#pragma unroll
        for (int rf = 0; rf < 2; ++rf)
#pragma unroll
            for (int cf = 0; cf < 2; ++cf) {
                int kidx = half * 2048 + ct * 32 + cf * 16 + (l & 15);
#pragma unroll
                for (int r = 0; r < 4; ++r) {
                    float v = ecf[cf] + acc[rf][cf][r];
                    if (v < minv[rf][r]) { minv[rf][r] = v; mini[rf][r] = kidx; }
                }
            }

        __syncthreads();
    }

#pragma unroll
    for (int off = 1; off < 16; off <<= 1) {
#pragma unroll
        for (int rf = 0; rf < 2; ++rf)
#pragma unroll
            for (int r = 0; r < 4; ++r) {
                float v2 = __shfl_xor(minv[rf][r], off);
                int   i2 = __shfl_xor(mini[rf][r], off);
                if (v2 < minv[rf][r] || (v2 == minv[rf][r] && i2 < mini[rf][r])) {
                    minv[rf][r] = v2; mini[rf][r] = i2;
                }
            }
    }
    if ((l & 15) == 0) {
#pragma unroll
        for (int rf = 0; rf < 2; ++rf)
#pragma unroll
            for (int r = 0; r < 4; ++r) {
                int row = row0 + w * 32 + rf * 16 + (l >> 4) * 4 + r;   // C/D: row=(l>>4)*4+reg
                pmin[(size_t)half * NPTS + row] = minv[rf][r];
                pidx[(size_t)half * NPTS + row] = mini[rf][r];
            }
    }
}

// ---------------- select: combine halves, write idx, quantize+loss, histogram ----------------
// 1024 blocks x 256 thr; 4 threads per row.
__global__ __launch_bounds__(256) void vq_select_kernel(const float* __restrict__ x,
                                                        const float* __restrict__ embed,
                                                        const float* __restrict__ pmin,
                                                        const int* __restrict__ pidx,
                                                        unsigned int* __restrict__ counts,
                                                        float* __restrict__ out) {
    __shared__ float red[256];
    __shared__ int   ks[64];
    int tid = threadIdx.x;

    if (tid < 64) {
        int rr = blockIdx.x * 64 + tid;
        float m0 = pmin[rr], m1 = pmin[NPTS + rr];
        int k = (m0 <= m1) ? pidx[rr] : pidx[NPTS + rr];   // half-0 wins ties (lower k)
        ks[tid] = k;
        out[OFF_IDX + rr] = (float)k;
        atomicAdd(&counts[k], 1u);
    }
    __syncthreads();

    int r  = blockIdx.x * 64 + (tid >> 2);
    int k  = ks[tid >> 2];
    int dq = (tid & 3) * 8;

    const float4* eg = (const float4*)embed + (size_t)k * 32 + dq;
    const float4* xg = (const float4*)x + (size_t)r * 32 + dq;
    float4*       qg = (float4*)out + (size_t)r * 32 + dq;

    float lsum = 0.f;
#pragma unroll
    for (int j = 0; j < 8; ++j) {
        float4 q = eg[j], xv = xg[j];
        qg[j] = q;
        float d0 = q.x - xv.x, d1 = q.y - xv.y, d2 = q.z - xv.z, d3 = q.w - xv.w;
        lsum += d0 * d0 + d1 * d1 + d2 * d2 + d3 * d3;
    }
    red[tid] = lsum;
    __syncthreads();
    for (int s = 128; s >= 1; s >>= 1) {
        if (tid < s) red[tid] += red[tid + s];
        __syncthreads();
    }
    if (tid == 0) atomicAdd(out + OFF_LOSS, red[0]);
}

// ---------------- scan: prefix-sum counts -> offsets/cursor; ncs, inv_sm, loss scale ----------------
// single block, 256 threads, 16 codes each.
__global__ __launch_bounds__(256) void vq_scan_kernel(const unsigned int* __restrict__ counts,
                                                      const float* __restrict__ cs,
                                                      float* __restrict__ out,
                                                      int* __restrict__ offsets,
                                                      int* __restrict__ cursor,
                                                      float* __restrict__ inv_sm) {
    __shared__ int   redi[256];
    __shared__ float redf[256];
    int tid = threadIdx.x;

    unsigned int c[16];
    int   csum = 0;
    float nsum = 0.f;
    float vl[16];
#pragma unroll
    for (int j = 0; j < 16; ++j) {
        int i = tid * 16 + j;
        c[j] = counts[i];
        csum += (int)c[j];
        float v = fmaf(cs[i], DECAY_F, (float)c[j] * ONE_MINUS_DECAY);
        vl[j] = v;
        nsum += v;
        out[OFF_NCS + i] = v;
    }

    // inclusive Hillis-Steele scan of per-thread sums
    redi[tid] = csum;
    redf[tid] = nsum;
    __syncthreads();
    for (int s = 1; s < 256; s <<= 1) {
        int v = (tid >= s) ? redi[tid - s] : 0;
        __syncthreads();
        redi[tid] += v;
        __syncthreads();
    }
    int excl = redi[tid] - csum;

    // total ncs sum
    for (int s = 128; s >= 1; s >>= 1) {
        if (tid < s) redf[tid] += redf[tid + s];
        __syncthreads();
    }
    float ntot = redf[0];
    float num  = ntot + (float)KCODES * EPS_F;

    int off = excl;
#pragma unroll
    for (int j = 0; j < 16; ++j) {
        int i = tid * 16 + j;
        offsets[i] = off;
        cursor[i]  = off;
        off += (int)c[j];
        inv_sm[i] = num / ((vl[j] + EPS_F) * ntot);
    }
    if (tid == 0) out[OFF_LOSS] *= 1.0f / ((float)NPTS * (float)DIM);
}

// ---------------- sort: bucket rows by code via cursor ----------------
__global__ __launch_bounds__(256) void vq_sort_kernel(const float* __restrict__ out,
                                                      int* __restrict__ cursor,
                                                      int* __restrict__ rowids) {
    int r = blockIdx.x * 256 + threadIdx.x;
    int k = (int)out[OFF_IDX + r];
    int pos = atomicAdd(&cursor[k], 1);
    rowids[pos] = r;
}

// ---------------- segsum: one wave per code; embed_sum + EMA + smoothing, no atomics ----------------
__global__ __launch_bounds__(256) void vq_segsum_kernel(const float* __restrict__ x,
                                                        const float* __restrict__ eavg,
                                                        const int* __restrict__ rowids,
                                                        const int* __restrict__ offsets,
                                                        const unsigned int* __restrict__ counts,
                                                        const float* __restrict__ inv_sm,
                                                        float* __restrict__ out) {
    int w = threadIdx.x >> 6, l = threadIdx.x & 63;
    int k = blockIdx.x * 4 + w;
    int off = offsets[k];
    int cnt = (int)counts[k];

    float a0 = 0.f, a1 = 0.f, b0 = 0.f, b1 = 0.f;
    int i = 0;
    for (; i + 2 <= cnt; i += 2) {
        int r0 = rowids[off + i], r1 = rowids[off + i + 1];
        float2 v0 = *(const float2*)(x + (size_t)r0 * DIM + l * 2);
        float2 v1 = *(const float2*)(x + (size_t)r1 * DIM + l * 2);
        a0 += v0.x; a1 += v0.y;
        b0 += v1.x; b1 += v1.y;
    }
    if (i < cnt) {
        int r0 = rowids[off + i];
        float2 v0 = *(const float2*)(x + (size_t)r0 * DIM + l * 2);
        a0 += v0.x; a1 += v0.y;
    }
    a0 += b0; a1 += b1;

    float2 ev = *(const float2*)(eavg + (size_t)k * DIM + l * 2);
    float ism = inv_sm[k];
    float2 o;
    o.x = fmaf(ev.x, DECAY_F, a0 * ONE_MINUS_DECAY) * ism;
    o.y = fmaf(ev.y, DECAY_F, a1 * ONE_MINUS_DECAY) * ism;
    *(float2*)(out + OFF_EMB + (size_t)k * DIM + l * 2) = o;
}

extern "C" void kernel_launch(void* const* d_in, const int* in_sizes, int n_in,
                              void* d_out, int out_size, void* d_ws, size_t ws_size,
                              hipStream_t stream) {
    const float* x     = (const float*)d_in[0];
    const float* embed = (const float*)d_in[1];
    const float* cs    = (const float*)d_in[2];
    const float* eavg  = (const float*)d_in[3];
    float* out = (float*)d_out;

    // ws: esq[4096] | inv_sm[4096] | pmin[2N] | pidx[2N] | counts[4096] | offsets[4096] |
    //     cursor[4096] | rowids[N] | Eimg 2MB   (~3.4 MB)
    float*         esq     = (float*)d_ws;
    float*         inv_sm  = esq + KCODES;
    float*         pmin    = inv_sm + KCODES;
    int*           pidx    = (int*)(pmin + 2 * NPTS);
    unsigned int*  counts  = (unsigned int*)(pidx + 2 * NPTS);
    int*           offsets = (int*)(counts + KCODES);
    int*           cursor  = offsets + KCODES;
    int*           rowids  = cursor + KCODES;
    unsigned char* Eimg    = (unsigned char*)(rowids + NPTS);

    hipMemsetAsync(counts, 0, KCODES * sizeof(unsigned int), stream);
    hipMemsetAsync(out + OFF_LOSS, 0, sizeof(float), stream);

    vq_esq_kernel<<<KCODES / 4, 256, 0, stream>>>(embed, esq);
    vq_eimg_kernel<<<KCODES / 32, 256, 0, stream>>>(embed, Eimg);
    vq_main_kernel<<<NPTS / 128 * 2, 256, 0, stream>>>(x, esq, Eimg, pmin, pidx);
    vq_select_kernel<<<NPTS / 64, 256, 0, stream>>>(x, embed, pmin, pidx, counts, out);
    vq_scan_kernel<<<1, 256, 0, stream>>>(counts, cs, out, offsets, cursor, inv_sm);
    vq_sort_kernel<<<NPTS / 256, 256, 0, stream>>>(out, cursor, rowids);
    vq_segsum_kernel<<<KCODES / 4, 256, 0, stream>>>(x, eavg, rowids, offsets, counts, inv_sm, out);
}

// Round 5
// 367.117 us; speedup vs baseline: 3.0113x; 1.0474x over previous
//
#include <hip/hip_runtime.h>
#include <math.h>

#define NPTS   65536
#define DIM    128
#define KCODES 4096

constexpr float DECAY_F         = 0.99f;
constexpr float ONE_MINUS_DECAY = 0.01f;
constexpr float EPS_F           = 1e-5f;

// d_out layout (floats): quantize_st[N*D] | embed_ind[N] | loss[1] | new_embed[K*D] | new_cluster_size[K]
constexpr int OFF_IDX  = NPTS * DIM;
constexpr int OFF_LOSS = OFF_IDX + NPTS;
constexpr int OFF_EMB  = OFF_LOSS + 1;
constexpr int OFF_NCS  = OFF_EMB + KCODES * DIM;

typedef _Float16 half8 __attribute__((ext_vector_type(8)));
typedef _Float16 half4 __attribute__((ext_vector_type(4)));
typedef float    f32x4 __attribute__((ext_vector_type(4)));

// ---------------- prep: E image + esq + ALL buffer init (no memsets needed) ----------------
// 128 blocks x 256 thr; block owns 32 codes.
__global__ __launch_bounds__(256) void vq_prep_kernel(const float* __restrict__ embed,
                                                      float* __restrict__ esq,
                                                      unsigned char* __restrict__ Eimg,
                                                      unsigned long long* __restrict__ rowpack,
                                                      unsigned int* __restrict__ counts,
                                                      float* __restrict__ out) {
    __shared__ float sq[512];
    int b = blockIdx.x, t = threadIdx.x;

    // init: rowpack (argmin combine slots), counts, loss
    rowpack[b * 512 + t]       = ~0ULL;
    rowpack[b * 512 + 256 + t] = ~0ULL;
    if (t < 32) counts[b * 32 + t] = 0u;
    if (b == 0 && t == 0) out[OFF_LOSS] = 0.f;

    unsigned char* img = Eimg + ((size_t)b << 14);
#pragma unroll
    for (int it = 0; it < 2; ++it) {
        int idx = t + it * 256;            // 0..511 : (r 0..31, c8 0..15)
        int r = idx >> 4, c8 = idx & 15;
        const float4* src = (const float4*)(embed + (size_t)(b * 32 + r) * DIM + c8 * 8);
        float4 v0 = src[0], v1 = src[1];
        float e[8] = {v0.x, v0.y, v0.z, v0.w, v1.x, v1.y, v1.z, v1.w};
        half8 h8, l8;
        float ss = 0.f;
#pragma unroll
        for (int j = 0; j < 8; ++j) {
            _Float16 h = (_Float16)e[j];
            h8[j] = h;
            l8[j] = (_Float16)(e[j] - (float)h);
            ss = fmaf(e[j], e[j], ss);
        }
        int bo = r * 256 + ((c8 * 16) ^ ((r & 7) << 4));
        *(half8*)(img + bo)        = h8;
        *(half8*)(img + 8192 + bo) = l8;
        sq[idx] = ss;
    }
    __syncthreads();
    if (t < 32) {
        float s = 0.f;
#pragma unroll
        for (int c = 0; c < 16; ++c) s += sq[t * 16 + c];
        esq[b * 32 + t] = s;
    }
}

// ---------------- main: K-split MFMA distance argmin + u64-atomicMin combine ----------------
__global__ __launch_bounds__(256, 4)
void vq_main_kernel(const float* __restrict__ x, const float* __restrict__ esq,
                    const unsigned char* __restrict__ Eimg,
                    unsigned long long* __restrict__ rowpack,
                    unsigned int* __restrict__ counts,
                    float* __restrict__ out) {
    __shared__ __align__(16) unsigned char lds[32768];

    const int tid  = threadIdx.x;
    const int l    = tid & 63;
    const int w    = tid >> 6;
    const int mblk = blockIdx.x >> 1;
    const int half = blockIdx.x & 1;
    const int row0 = mblk * 128;

    // ---- X prologue: two 64-row phases through LDS; A = -2x f16 hi/lo -> registers ----
    half8 ahi[2][4], alo[2][4];
#pragma unroll
    for (int ph = 0; ph < 2; ++ph) {
        if (ph) __syncthreads();
        const float4* xg = (const float4*)(x + (size_t)(row0 + ph * 64) * DIM);
#pragma unroll
        for (int it = 0; it < 8; ++it) {
            int i4 = tid + it * 256;           // 0..2047 : 64 rows x 32 f4
            int r = i4 >> 5, c4 = i4 & 31;
            float4 v = xg[i4];
            float m0 = -2.f * v.x, m1 = -2.f * v.y, m2 = -2.f * v.z, m3 = -2.f * v.w;
            half4 h, lo;
            h[0] = (_Float16)m0; h[1] = (_Float16)m1; h[2] = (_Float16)m2; h[3] = (_Float16)m3;
            lo[0] = (_Float16)(m0 - (float)h[0]); lo[1] = (_Float16)(m1 - (float)h[1]);
            lo[2] = (_Float16)(m2 - (float)h[2]); lo[3] = (_Float16)(m3 - (float)h[3]);
            int bo = r * 256 + ((c4 * 8) ^ ((r & 7) << 4));
            *(half4*)(lds + bo)         = h;
            *(half4*)(lds + 16384 + bo) = lo;
        }
        __syncthreads();
        if ((w >> 1) == ph) {
#pragma unroll
            for (int rf = 0; rf < 2; ++rf)
#pragma unroll
                for (int ks = 0; ks < 4; ++ks) {
                    int rloc = (w & 1) * 32 + rf * 16 + (l & 15);
                    int bo = rloc * 256 + ((ks * 64 + (l >> 4) * 16) ^ ((rloc & 7) << 4));
                    ahi[rf][ks] = *(const half8*)(lds + bo);
                    alo[rf][ks] = *(const half8*)(lds + 16384 + bo);
                }
        }
    }
    __syncthreads();   // frag loads done; lds becomes E double-buffer (16KB each)

#define STAGE(P, CT)                                                                     \
    {                                                                                    \
        const unsigned char* gsrc = Eimg + ((size_t)(half * 64 + (CT)) << 14);           \
        _Pragma("unroll")                                                                \
        for (int t = 0; t < 4; ++t) {                                                    \
            __builtin_amdgcn_global_load_lds(                                            \
                (const __attribute__((address_space(1))) unsigned int*)(gsrc + t * 4096 + w * 1024 + l * 16), \
                (__attribute__((address_space(3))) unsigned int*)(lds + (P) * 16384 + t * 4096 + w * 1024),   \
                16, 0, 0);                                                               \
        }                                                                                \
    }

    float minv[2][4];
    int   mini[2][4];
#pragma unroll
    for (int rf = 0; rf < 2; ++rf)
#pragma unroll
        for (int r = 0; r < 4; ++r) { minv[rf][r] = 3.4e38f; mini[rf][r] = 0; }

    STAGE(0, 0);
    __syncthreads();

    for (int ct = 0; ct < 64; ++ct) {
        int p = ct & 1;
        if (ct < 63) STAGE(p ^ 1, ct + 1);
        const unsigned char* bb = lds + p * 16384;

        float ecf[2];
#pragma unroll
        for (int cf = 0; cf < 2; ++cf) ecf[cf] = esq[half * 2048 + ct * 32 + cf * 16 + (l & 15)];

        f32x4 acc[2][2];
#pragma unroll
        for (int rf = 0; rf < 2; ++rf)
#pragma unroll
            for (int cf = 0; cf < 2; ++cf) acc[rf][cf] = (f32x4){0.f, 0.f, 0.f, 0.f};

#pragma unroll
        for (int ks = 0; ks < 4; ++ks) {
#pragma unroll
            for (int cf = 0; cf < 2; ++cf) {
                int rowb = cf * 16 + (l & 15);
                int bo = rowb * 256 + ((ks * 64 + (l >> 4) * 16) ^ ((rowb & 7) << 4));
                half8 bh = *(const half8*)(bb + bo);
                half8 bl = *(const half8*)(bb + 8192 + bo);
                acc[0][cf] = __builtin_amdgcn_mfma_f32_16x16x32_f16(ahi[0][ks], bh, acc[0][cf], 0, 0, 0);
                acc[1][cf] = __builtin_amdgcn_mfma_f32_16x16x32_f16(ahi[1][ks], bh, acc[1][cf], 0, 0, 0);
                acc[0][cf] = __builtin_amdgcn_mfma_f32_16x16x32_f16(alo[0][ks], bh, acc[0][cf], 0, 0, 0);
                acc[1][cf] = __builtin_amdgcn_mfma_f32_16x16x32_f16(alo[1][ks], bh, acc[1][cf], 0, 0, 0);
                acc[0][cf] = __builtin_amdgcn_mfma_f32_16x16x32_f16(ahi[0][ks], bl, acc[0][cf], 0, 0, 0);
                acc[1][cf] = __builtin_amdgcn_mfma_f32_16x16x32_f16(ahi[1][ks], bl, acc[1][cf], 0, 0, 0);
            }
        }

#pragma unroll
        for (int rf = 0; rf < 2; ++rf)
#pragma unroll
            for (int cf = 0; cf < 2; ++cf) {
                int kidx = half * 2048 + ct * 32 + cf * 16 + (l & 15);
#pragma unroll
                for (int r = 0; r < 4; ++r) {
                    float v = ecf[cf] + acc[rf][cf][r];
                    if (v < minv[rf][r]) { minv[rf][r] = v; mini[rf][r] = kidx; }
                }
            }

        __syncthreads();
    }

    // argmin reduce across the 16 col-lanes (low 4 lane bits)
#pragma unroll
    for (int off = 1; off < 16; off <<= 1) {
#pragma unroll
        for (int rf = 0; rf < 2; ++rf)
#pragma unroll
            for (int r = 0; r < 4; ++r) {
                float v2 = __shfl_xor(minv[rf][r], off);
                int   i2 = __shfl_xor(mini[rf][r], off);
                if (v2 < minv[rf][r] || (v2 == minv[rf][r] && i2 < mini[rf][r])) {
                    minv[rf][r] = v2; mini[rf][r] = i2;
                }
            }
    }
    // combine halves in place: key = (monotonic(score)<<32)|idx, atomicMin.
    // Second arriver (old != INIT) knows the global winner -> idx write + histogram.
    if ((l & 15) == 0) {
#pragma unroll
        for (int rf = 0; rf < 2; ++rf)
#pragma unroll
            for (int r = 0; r < 4; ++r) {
                int row = row0 + w * 32 + rf * 16 + (l >> 4) * 4 + r;   // C/D: row=(l>>4)*4+reg
                unsigned int u = __float_as_uint(minv[rf][r]);
                u = (u & 0x80000000u) ? ~u : (u | 0x80000000u);
                unsigned long long key = ((unsigned long long)u << 32) | (unsigned int)mini[rf][r];
                unsigned long long old = atomicMin(&rowpack[row], key);
                if (old != ~0ULL) {
                    unsigned long long fin = old < key ? old : key;
                    int kf = (int)(fin & 0xFFFFFFFFu);
                    out[OFF_IDX + row] = (float)kf;
                    atomicAdd(&counts[kf], 1u);
                }
            }
    }
}

// ---------------- scan: prefix-sum counts -> offsets/cursor; ncs, inv_sm ----------------
// single block, 1024 threads, 4 codes each.
__global__ __launch_bounds__(1024) void vq_scan_kernel(const unsigned int* __restrict__ counts,
                                                       const float* __restrict__ cs,
                                                       float* __restrict__ out,
                                                       int* __restrict__ offsets,
                                                       int* __restrict__ cursor,
                                                       float* __restrict__ inv_sm) {
    __shared__ int   redi[1024];
    __shared__ float redf[1024];
    int tid = threadIdx.x;

    unsigned int c[4];
    float vl[4];
    int   csum = 0;
    float nsum = 0.f;
#pragma unroll
    for (int j = 0; j < 4; ++j) {
        int i = tid * 4 + j;
        c[j] = counts[i];
        csum += (int)c[j];
        float v = fmaf(cs[i], DECAY_F, (float)c[j] * ONE_MINUS_DECAY);
        vl[j] = v;
        nsum += v;
        out[OFF_NCS + i] = v;
    }

    redi[tid] = csum;
    redf[tid] = nsum;
    __syncthreads();
    for (int s = 1; s < 1024; s <<= 1) {
        int v = (tid >= s) ? redi[tid - s] : 0;
        __syncthreads();
        redi[tid] += v;
        __syncthreads();
    }
    int excl = redi[tid] - csum;

    for (int s = 512; s >= 1; s >>= 1) {
        if (tid < s) redf[tid] += redf[tid + s];
        __syncthreads();
    }
    float ntot = redf[0];
    float num  = ntot + (float)KCODES * EPS_F;

    int off = excl;
#pragma unroll
    for (int j = 0; j < 4; ++j) {
        int i = tid * 4 + j;
        offsets[i] = off;
        cursor[i]  = off;
        off += (int)c[j];
        inv_sm[i] = num / ((vl[j] + EPS_F) * ntot);
    }
}

// ---------------- sort: bucket rows by code via cursor ----------------
__global__ __launch_bounds__(256) void vq_sort_kernel(const float* __restrict__ out,
                                                      int* __restrict__ cursor,
                                                      int* __restrict__ rowids) {
    int r = blockIdx.x * 256 + threadIdx.x;
    int k = (int)out[OFF_IDX + r];
    int pos = atomicAdd(&cursor[k], 1);
    rowids[pos] = r;
}

// ---------------- segsum: one wave per code; embed_sum + EMA + quantize + loss ----------------
__global__ __launch_bounds__(256) void vq_segsum_kernel(const float* __restrict__ x,
                                                        const float* __restrict__ embed,
                                                        const float* __restrict__ eavg,
                                                        const int* __restrict__ rowids,
                                                        const int* __restrict__ offsets,
                                                        const unsigned int* __restrict__ counts,
                                                        const float* __restrict__ inv_sm,
                                                        float* __restrict__ out) {
    __shared__ float red[256];
    int tid = threadIdx.x;
    int w = tid >> 6, l = tid & 63;
    int k = blockIdx.x * 4 + w;
    int off = offsets[k];
    int cnt = (int)counts[k];

    float2 e2 = *(const float2*)(embed + (size_t)k * DIM + l * 2);

    float a0 = 0.f, a1 = 0.f, b0 = 0.f, b1 = 0.f;
    float lsum = 0.f;
    int i = 0;
    for (; i + 2 <= cnt; i += 2) {
        int r0 = rowids[off + i], r1 = rowids[off + i + 1];
        float2 v0 = *(const float2*)(x + (size_t)r0 * DIM + l * 2);
        float2 v1 = *(const float2*)(x + (size_t)r1 * DIM + l * 2);
        a0 += v0.x; a1 += v0.y;
        b0 += v1.x; b1 += v1.y;
        *(float2*)(out + (size_t)r0 * DIM + l * 2) = e2;   // quantize gather (code-major)
        *(float2*)(out + (size_t)r1 * DIM + l * 2) = e2;
        float d0 = e2.x - v0.x, d1 = e2.y - v0.y;
        float d2 = e2.x - v1.x, d3 = e2.y - v1.y;
        lsum += d0 * d0 + d1 * d1 + d2 * d2 + d3 * d3;
    }
    if (i < cnt) {
        int r0 = rowids[off + i];
        float2 v0 = *(const float2*)(x + (size_t)r0 * DIM + l * 2);
        a0 += v0.x; a1 += v0.y;
        *(float2*)(out + (size_t)r0 * DIM + l * 2) = e2;
        float d0 = e2.x - v0.x, d1 = e2.y - v0.y;
        lsum += d0 * d0 + d1 * d1;
    }
    a0 += b0; a1 += b1;

    float2 ev = *(const float2*)(eavg + (size_t)k * DIM + l * 2);
    float ism = inv_sm[k];
    float2 o;
    o.x = fmaf(ev.x, DECAY_F, a0 * ONE_MINUS_DECAY) * ism;
    o.y = fmaf(ev.y, DECAY_F, a1 * ONE_MINUS_DECAY) * ism;
    *(float2*)(out + OFF_EMB + (size_t)k * DIM + l * 2) = o;

    red[tid] = lsum;
    __syncthreads();
    for (int s = 128; s >= 1; s >>= 1) {
        if (tid < s) red[tid] += red[tid + s];
        __syncthreads();
    }
    if (tid == 0) atomicAdd(out + OFF_LOSS, red[0] * (1.0f / ((float)NPTS * (float)DIM)));
}

extern "C" void kernel_launch(void* const* d_in, const int* in_sizes, int n_in,
                              void* d_out, int out_size, void* d_ws, size_t ws_size,
                              hipStream_t stream) {
    const float* x     = (const float*)d_in[0];
    const float* embed = (const float*)d_in[1];
    const float* cs    = (const float*)d_in[2];
    const float* eavg  = (const float*)d_in[3];
    float* out = (float*)d_out;

    // ws: rowpack[N] u64 | esq[K] | inv_sm[K] | counts[K] | offsets[K] | cursor[K] |
    //     rowids[N] | Eimg 2MB   (~2.9 MB; Eimg offset 16B-aligned)
    unsigned long long* rowpack = (unsigned long long*)d_ws;
    float*         esq     = (float*)(rowpack + NPTS);
    float*         inv_sm  = esq + KCODES;
    unsigned int*  counts  = (unsigned int*)(inv_sm + KCODES);
    int*           offsets = (int*)(counts + KCODES);
    int*           cursor  = offsets + KCODES;
    int*           rowids  = cursor + KCODES;
    unsigned char* Eimg    = (unsigned char*)(rowids + NPTS);

    vq_prep_kernel<<<KCODES / 32, 256, 0, stream>>>(embed, esq, Eimg, rowpack, counts, out);
    vq_main_kernel<<<NPTS / 128 * 2, 256, 0, stream>>>(x, esq, Eimg, rowpack, counts, out);
    vq_scan_kernel<<<1, 1024, 0, stream>>>(counts, cs, out, offsets, cursor, inv_sm);
    vq_sort_kernel<<<NPTS / 256, 256, 0, stream>>>(out, cursor, rowids);
    vq_segsum_kernel<<<KCODES / 4, 256, 0, stream>>>(x, embed, eavg, rowids, offsets, counts, inv_sm, out);
}